// Round 1
// baseline (935.920 us; speedup 1.0000x reference)
//
#include <hip/hip_runtime.h>
#include <hip/hip_bf16.h>
#include <cstdint>
#include <cstddef>

// Problem constants
#define BB   8192
#define DIN  1024
#define DD   768
#define CC   16384

typedef __bf16 bf16x8 __attribute__((ext_vector_type(8)));
typedef __bf16 bf16x4 __attribute__((ext_vector_type(4)));
typedef float  floatx4 __attribute__((ext_vector_type(4)));

__device__ __forceinline__ void gload_lds16(const void* g, void* l) {
    __builtin_amdgcn_global_load_lds(
        (const __attribute__((address_space(1))) void*)g,
        (__attribute__((address_space(3))) void*)l,
        16, 0, 0);
}

// ---------------- prep kernels ----------------

// fp32 -> bf16, 4 elements/thread (exact grid, n4 = n/4)
__global__ __launch_bounds__(256) void f2b_kernel(const float4* __restrict__ in,
                                                  bf16x4* __restrict__ out) {
    size_t i = (size_t)blockIdx.x * 256 + threadIdx.x;
    float4 v = in[i];
    bf16x4 o;
    o.x = (__bf16)v.x; o.y = (__bf16)v.y; o.z = (__bf16)v.z; o.w = (__bf16)v.w;
    out[i] = o;
}

// per-row: convert fp32 row -> bf16 row, and sumsq of the *rounded* values -> sq[row]
__global__ __launch_bounds__(256) void row_convert_sumsq_f32(const float* __restrict__ src,
                                                             __bf16* __restrict__ dst,
                                                             float* __restrict__ sq,
                                                             int Dd) {
    int row = blockIdx.x;
    int tid = threadIdx.x, lane = tid & 63, wave = tid >> 6;
    const float* s = src + (size_t)row * Dd;
    __bf16* d = dst + (size_t)row * Dd;
    float acc = 0.f;
    for (int j = tid; j < Dd; j += 256) {
        __bf16 b = (__bf16)s[j];
        d[j] = b;
        float f = (float)b;
        acc += f * f;
    }
    for (int off = 32; off > 0; off >>= 1) acc += __shfl_xor(acc, off, 64);
    __shared__ float red[4];
    if (lane == 0) red[wave] = acc;
    __syncthreads();
    if (tid == 0) sq[row] = red[0] + red[1] + red[2] + red[3];
}

// per-row sumsq of a bf16 matrix
__global__ __launch_bounds__(256) void row_sumsq_bf16(const __bf16* __restrict__ src,
                                                      float* __restrict__ sq,
                                                      int Dd) {
    int row = blockIdx.x;
    int tid = threadIdx.x, lane = tid & 63, wave = tid >> 6;
    const __bf16* s = src + (size_t)row * Dd;
    float acc = 0.f;
    for (int j = tid; j < Dd; j += 256) {
        float f = (float)s[j];
        acc += f * f;
    }
    for (int off = 32; off > 0; off >>= 1) acc += __shfl_xor(acc, off, 64);
    __shared__ float red[4];
    if (lane == 0) red[wave] = acc;
    __syncthreads();
    if (tid == 0) sq[row] = red[0] + red[1] + red[2] + red[3];
}

// W [K x N] fp32 -> Wt [N x K] bf16  (K=1024, N=768)
__global__ __launch_bounds__(256) void transpose_w(const float* __restrict__ W,
                                                   __bf16* __restrict__ Wt,
                                                   int K, int N) {
    __shared__ float tile[32][33];
    int bx = blockIdx.x * 32;  // along N
    int by = blockIdx.y * 32;  // along K
    int tx = threadIdx.x & 31, ty = threadIdx.x >> 5;  // ty 0..7
    for (int i = 0; i < 32; i += 8)
        tile[ty + i][tx] = W[(size_t)(by + ty + i) * N + bx + tx];
    __syncthreads();
    for (int i = 0; i < 32; i += 8)
        Wt[(size_t)(bx + ty + i) * K + by + tx] = (__bf16)tile[tx][ty + i];
}

// ---------------- GEMM (m97 structure): D = A[MxK] * Bt[NxK]^T ----------------
// EPI==0: store bf16 raw (for e). EPI==1: out = 2*acc - esq[row] - csq[col], fp32.
template <int EPI>
__global__ __launch_bounds__(256) void gemm_bt(const __bf16* __restrict__ A,
                                               const __bf16* __restrict__ Bt,
                                               void* __restrict__ OutP,
                                               const float* __restrict__ esq,
                                               const float* __restrict__ csq,
                                               int M, int N, int K) {
    __shared__ __bf16 As[128 * 64];
    __shared__ __bf16 Bs[128 * 64];
    const int tid  = threadIdx.x;
    const int lane = tid & 63;
    const int wave = tid >> 6;
    const int bm = blockIdx.x * 128;
    const int bn = blockIdx.y * 128;

    floatx4 acc[4][4] = {};

    const int srow = lane >> 3;        // 0..7 (row within 8-row staging chunk)
    const int sk   = (lane & 7) * 8;   // k element offset of the 16B chunk

    const int wm   = (wave & 1) * 64;  // wave's 64x64 subtile
    const int wn   = (wave >> 1) * 64;
    const int frow = lane & 15;
    const int fk   = (lane >> 4) * 8;

    for (int k0 = 0; k0 < K; k0 += 64) {
        __syncthreads();  // previous compute phase done before overwriting LDS
        #pragma unroll
        for (int i = 0; i < 4; ++i) {
            int row = wave * 32 + i * 8;  // wave-uniform chunk base
            const __bf16* ga = A  + (size_t)(bm + row + srow) * K + k0 + sk;
            gload_lds16(ga, &As[(size_t)row * 64]);
            const __bf16* gb = Bt + (size_t)(bn + row + srow) * K + k0 + sk;
            gload_lds16(gb, &Bs[(size_t)row * 64]);
        }
        asm volatile("s_waitcnt vmcnt(0)" ::: "memory");
        __syncthreads();

        #pragma unroll
        for (int kk = 0; kk < 64; kk += 32) {
            bf16x8 af[4], bfr[4];
            #pragma unroll
            for (int mi = 0; mi < 4; ++mi)
                af[mi] = *(const bf16x8*)&As[(wm + mi * 16 + frow) * 64 + kk + fk];
            #pragma unroll
            for (int ni = 0; ni < 4; ++ni)
                bfr[ni] = *(const bf16x8*)&Bs[(wn + ni * 16 + frow) * 64 + kk + fk];
            #pragma unroll
            for (int mi = 0; mi < 4; ++mi)
                #pragma unroll
                for (int ni = 0; ni < 4; ++ni)
                    acc[mi][ni] = __builtin_amdgcn_mfma_f32_16x16x32_bf16(
                        af[mi], bfr[ni], acc[mi][ni], 0, 0, 0);
        }
    }

    // epilogue: C/D layout col=lane&15, row=(lane>>4)*4+reg
    const int colw = lane & 15;
    const int rowq = (lane >> 4) * 4;
    if (EPI == 1) {
        float* Out = (float*)OutP;
        #pragma unroll
        for (int mi = 0; mi < 4; ++mi) {
            #pragma unroll
            for (int ni = 0; ni < 4; ++ni) {
                int col = bn + wn + ni * 16 + colw;
                float cs = csq[col];
                #pragma unroll
                for (int r = 0; r < 4; ++r) {
                    int row = bm + wm + mi * 16 + rowq + r;
                    Out[(size_t)row * N + col] = 2.0f * acc[mi][ni][r] - esq[row] - cs;
                }
            }
        }
    } else {
        __bf16* Out = (__bf16*)OutP;
        #pragma unroll
        for (int mi = 0; mi < 4; ++mi) {
            #pragma unroll
            for (int ni = 0; ni < 4; ++ni) {
                int col = bn + wn + ni * 16 + colw;
                #pragma unroll
                for (int r = 0; r < 4; ++r) {
                    int row = bm + wm + mi * 16 + rowq + r;
                    Out[(size_t)row * N + col] = (__bf16)acc[mi][ni][r];
                }
            }
        }
    }
}

// ---------------- launch ----------------

extern "C" void kernel_launch(void* const* d_in, const int* in_sizes, int n_in,
                              void* d_out, int out_size, void* d_ws, size_t ws_size,
                              hipStream_t stream) {
    const float* x    = (const float*)d_in[0];  // [B, DIN]
    const float* W    = (const float*)d_in[1];  // [DIN, D]
    const float* cent = (const float*)d_in[2];  // [C, D]
    float* out = (float*)d_out;                 // [B, C]

    char* ws = (char*)d_ws;
    __bf16* xb  = (__bf16*)ws;  ws += (size_t)BB * DIN * 2;   // 16 MB
    __bf16* Wt  = (__bf16*)ws;  ws += (size_t)DD * DIN * 2;   // 1.5 MB
    __bf16* cb  = (__bf16*)ws;  ws += (size_t)CC * DD * 2;    // 24 MB
    float*  csq = (float*)ws;   ws += (size_t)CC * 4;
    __bf16* eb  = (__bf16*)ws;  ws += (size_t)BB * DD * 2;    // 12 MB
    float*  esq = (float*)ws;   ws += (size_t)BB * 4;

    // 1. x -> bf16 (8M elems, 4/thread)
    f2b_kernel<<<(BB * DIN) / (256 * 4), 256, 0, stream>>>((const float4*)x, (bf16x4*)xb);
    // 2. W [DIN x D] -> Wt [D x DIN] bf16
    transpose_w<<<dim3(DD / 32, DIN / 32), 256, 0, stream>>>(W, Wt, DIN, DD);
    // 3. centroids -> bf16 + c_sq (from rounded values)
    row_convert_sumsq_f32<<<CC, 256, 0, stream>>>(cent, cb, csq, DD);
    // 4. e = x @ W  (M=8192, N=768, K=1024), store bf16
    gemm_bt<0><<<dim3(BB / 128, DD / 128), 256, 0, stream>>>(xb, Wt, eb, nullptr, nullptr,
                                                             BB, DD, DIN);
    // 5. e_sq from rounded e
    row_sumsq_bf16<<<BB, 256, 0, stream>>>(eb, esq, DD);
    // 6. out = 2 * e@centT - e_sq - c_sq  (M=8192, N=16384, K=768)
    gemm_bt<1><<<dim3(BB / 128, CC / 128), 256, 0, stream>>>(eb, cb, out, esq, csq,
                                                             BB, CC, DD);
}

// Round 2
// 830.115 us; speedup vs baseline: 1.1275x; 1.1275x over previous
//
#include <hip/hip_runtime.h>
#include <hip/hip_bf16.h>
#include <cstdint>
#include <cstddef>

// Problem constants
#define BB   8192
#define DIN  1024
#define DD   768
#define CC   16384

typedef __bf16 bf16x8 __attribute__((ext_vector_type(8)));
typedef __bf16 bf16x4 __attribute__((ext_vector_type(4)));
typedef float  floatx4 __attribute__((ext_vector_type(4)));

__device__ __forceinline__ void gload_lds16(const void* g, void* l) {
    __builtin_amdgcn_global_load_lds(
        (const __attribute__((address_space(1))) void*)g,
        (__attribute__((address_space(3))) void*)l,
        16, 0, 0);
}

// ---------------- prep kernels ----------------

// fp32 -> bf16, 4 elements/thread (exact grid)
__global__ __launch_bounds__(256) void f2b_kernel(const float4* __restrict__ in,
                                                  bf16x4* __restrict__ out) {
    size_t i = (size_t)blockIdx.x * 256 + threadIdx.x;
    float4 v = in[i];
    bf16x4 o;
    o.x = (__bf16)v.x; o.y = (__bf16)v.y; o.z = (__bf16)v.z; o.w = (__bf16)v.w;
    out[i] = o;
}

// per-row: convert fp32 row -> bf16 row, and sumsq of the *rounded* values -> sq[row]
__global__ __launch_bounds__(256) void row_convert_sumsq_f32(const float* __restrict__ src,
                                                             __bf16* __restrict__ dst,
                                                             float* __restrict__ sq,
                                                             int Dd) {
    int row = blockIdx.x;
    int tid = threadIdx.x, lane = tid & 63, wave = tid >> 6;
    const float* s = src + (size_t)row * Dd;
    __bf16* d = dst + (size_t)row * Dd;
    float acc = 0.f;
    for (int j = tid; j < Dd; j += 256) {
        __bf16 b = (__bf16)s[j];
        d[j] = b;
        float f = (float)b;
        acc += f * f;
    }
    for (int off = 32; off > 0; off >>= 1) acc += __shfl_xor(acc, off, 64);
    __shared__ float red[4];
    if (lane == 0) red[wave] = acc;
    __syncthreads();
    if (tid == 0) sq[row] = red[0] + red[1] + red[2] + red[3];
}

// per-row sumsq of a bf16 matrix
__global__ __launch_bounds__(256) void row_sumsq_bf16(const __bf16* __restrict__ src,
                                                      float* __restrict__ sq,
                                                      int Dd) {
    int row = blockIdx.x;
    int tid = threadIdx.x, lane = tid & 63, wave = tid >> 6;
    const __bf16* s = src + (size_t)row * Dd;
    float acc = 0.f;
    for (int j = tid; j < Dd; j += 256) {
        float f = (float)s[j];
        acc += f * f;
    }
    for (int off = 32; off > 0; off >>= 1) acc += __shfl_xor(acc, off, 64);
    __shared__ float red[4];
    if (lane == 0) red[wave] = acc;
    __syncthreads();
    if (tid == 0) sq[row] = red[0] + red[1] + red[2] + red[3];
}

// W [K x N] fp32 -> Wt [N x K] bf16  (K=1024, N=768)
__global__ __launch_bounds__(256) void transpose_w(const float* __restrict__ W,
                                                   __bf16* __restrict__ Wt,
                                                   int K, int N) {
    __shared__ float tile[32][33];
    int bx = blockIdx.x * 32;  // along N
    int by = blockIdx.y * 32;  // along K
    int tx = threadIdx.x & 31, ty = threadIdx.x >> 5;  // ty 0..7
    for (int i = 0; i < 32; i += 8)
        tile[ty + i][tx] = W[(size_t)(by + ty + i) * N + bx + tx];
    __syncthreads();
    for (int i = 0; i < 32; i += 8)
        Wt[(size_t)(bx + ty + i) * K + by + tx] = (__bf16)tile[tx][ty + i];
}

// ---------------- GEMM (m97 structure): D = A[MxK] * Bt[NxK]^T ----------------
// LDS chunk-XOR swizzle (c' = c ^ (row&7)) applied on the GLOBAL address side so
// global_load_lds's lane->base+lane*16 mapping realizes it; fragment ds_read_b128
// then spreads across all 32 banks (2-way aliasing only = free).
// MFMA operands SWAPPED (bfr first) so C/D layout gives each thread 4 consecutive
// N-columns at a fixed M-row -> float4/bf16x4 stores.
// EPI==0: store bf16 raw (for e). EPI==1: out = 2*acc - esq[row] - csq[col], fp32 nt.
// SWIZ==1: 1D grid 8192 blocks, XCD-stripe swizzle (each XCD owns 16 bn tiles).
template <int EPI, int SWIZ>
__global__ __launch_bounds__(256) void gemm_bt(const __bf16* __restrict__ A,
                                               const __bf16* __restrict__ Bt,
                                               void* __restrict__ OutP,
                                               const float* __restrict__ esq,
                                               const float* __restrict__ csq,
                                               int M, int N, int K) {
    __shared__ __bf16 As[128 * 64];
    __shared__ __bf16 Bs[128 * 64];
    const int tid  = threadIdx.x;
    const int lane = tid & 63;
    const int wave = tid >> 6;

    int bm, bn;
    if (SWIZ == 1) {
        // grid = 8192, M-tiles = 64, N-tiles = 128: XCD x owns bn stripe [x*16, x*16+16)
        int flat = blockIdx.x;
        int xcd = flat & 7;
        int j = flat >> 3;                 // 0..1023
        bn = (xcd * 16 + (j & 15)) * 128;
        bm = (j >> 4) * 128;
    } else {
        int flat = blockIdx.x;
        int nt = N / 128;
        bm = (flat / nt) * 128;
        bn = (flat % nt) * 128;
    }

    floatx4 acc[4][4] = {};

    const int srow = lane >> 3;                         // 0..7 row within 8-row chunk
    const int sc   = ((lane & 7) ^ srow) * 8;           // swizzled k-chunk (elements)

    const int wm   = (wave & 1) * 64;  // wave's 64x64 subtile
    const int wn   = (wave >> 1) * 64;
    const int frow = lane & 15;
    const int quad = lane >> 4;
    const int swz  = frow & 7;

    for (int k0 = 0; k0 < K; k0 += 64) {
        __syncthreads();  // previous compute phase done before overwriting LDS
        #pragma unroll
        for (int i = 0; i < 4; ++i) {
            int row = wave * 32 + i * 8;  // wave-uniform chunk base
            const __bf16* ga = A  + (size_t)(bm + row + srow) * K + k0 + sc;
            gload_lds16(ga, &As[(size_t)row * 64]);
            const __bf16* gb = Bt + (size_t)(bn + row + srow) * K + k0 + sc;
            gload_lds16(gb, &Bs[(size_t)row * 64]);
        }
        asm volatile("s_waitcnt vmcnt(0)" ::: "memory");
        __syncthreads();

        #pragma unroll
        for (int kb = 0; kb < 2; ++kb) {
            bf16x8 af[4], bfr[4];
            #pragma unroll
            for (int mi = 0; mi < 4; ++mi)
                af[mi] = *(const bf16x8*)&As[(wm + mi * 16 + frow) * 64 +
                                             (((kb * 4 + quad) ^ swz) * 8)];
            #pragma unroll
            for (int ni = 0; ni < 4; ++ni)
                bfr[ni] = *(const bf16x8*)&Bs[(wn + ni * 16 + frow) * 64 +
                                              (((kb * 4 + quad) ^ swz) * 8)];
            #pragma unroll
            for (int mi = 0; mi < 4; ++mi)
                #pragma unroll
                for (int ni = 0; ni < 4; ++ni)
                    // swapped operands: D's "col"(lane&15) dim = M, "row"(quad*4+r) = N
                    acc[mi][ni] = __builtin_amdgcn_mfma_f32_16x16x32_bf16(
                        bfr[ni], af[mi], acc[mi][ni], 0, 0, 0);
        }
    }

    // epilogue (swapped layout): M-row = lane&15, N-col base = (lane>>4)*4, 4 regs = 4 cols
    const int mrow = lane & 15;
    const int nq   = (lane >> 4) * 4;
    if (EPI == 1) {
        float* Out = (float*)OutP;
        #pragma unroll
        for (int mi = 0; mi < 4; ++mi) {
            int row = bm + wm + mi * 16 + mrow;
            float es = esq[row];
            size_t rb = (size_t)row * N;
            #pragma unroll
            for (int ni = 0; ni < 4; ++ni) {
                int col = bn + wn + ni * 16 + nq;
                floatx4 cs = *(const floatx4*)&csq[col];
                floatx4 a = acc[mi][ni];
                floatx4 v;
                #pragma unroll
                for (int r = 0; r < 4; ++r)
                    v[r] = 2.0f * a[r] - es - cs[r];
                __builtin_nontemporal_store(v, (floatx4*)&Out[rb + col]);
            }
        }
    } else {
        __bf16* Out = (__bf16*)OutP;
        #pragma unroll
        for (int mi = 0; mi < 4; ++mi) {
            int row = bm + wm + mi * 16 + mrow;
            size_t rb = (size_t)row * N;
            #pragma unroll
            for (int ni = 0; ni < 4; ++ni) {
                int col = bn + wn + ni * 16 + nq;
                floatx4 a = acc[mi][ni];
                bf16x4 o;
                #pragma unroll
                for (int r = 0; r < 4; ++r) o[r] = (__bf16)a[r];
                *(bf16x4*)&Out[rb + col] = o;
            }
        }
    }
}

// ---------------- launch ----------------

extern "C" void kernel_launch(void* const* d_in, const int* in_sizes, int n_in,
                              void* d_out, int out_size, void* d_ws, size_t ws_size,
                              hipStream_t stream) {
    const float* x    = (const float*)d_in[0];  // [B, DIN]
    const float* W    = (const float*)d_in[1];  // [DIN, D]
    const float* cent = (const float*)d_in[2];  // [C, D]
    float* out = (float*)d_out;                 // [B, C]

    char* ws = (char*)d_ws;
    __bf16* xb  = (__bf16*)ws;  ws += (size_t)BB * DIN * 2;   // 16 MB
    __bf16* Wt  = (__bf16*)ws;  ws += (size_t)DD * DIN * 2;   // 1.5 MB
    __bf16* cb  = (__bf16*)ws;  ws += (size_t)CC * DD * 2;    // 24 MB
    float*  csq = (float*)ws;   ws += (size_t)CC * 4;
    __bf16* eb  = (__bf16*)ws;  ws += (size_t)BB * DD * 2;    // 12 MB
    float*  esq = (float*)ws;   ws += (size_t)BB * 4;

    // 1. x -> bf16 (8M elems, 4/thread)
    f2b_kernel<<<(BB * DIN) / (256 * 4), 256, 0, stream>>>((const float4*)x, (bf16x4*)xb);
    // 2. W [DIN x D] -> Wt [D x DIN] bf16
    transpose_w<<<dim3(DD / 32, DIN / 32), 256, 0, stream>>>(W, Wt, DIN, DD);
    // 3. centroids -> bf16 + c_sq (from rounded values)
    row_convert_sumsq_f32<<<CC, 256, 0, stream>>>(cent, cb, csq, DD);
    // 4. e = x @ W  (M=8192, N=768, K=1024), store bf16
    gemm_bt<0, 0><<<(BB / 128) * (DD / 128), 256, 0, stream>>>(xb, Wt, eb, nullptr, nullptr,
                                                               BB, DD, DIN);
    // 5. e_sq from rounded e
    row_sumsq_bf16<<<BB, 256, 0, stream>>>(eb, esq, DD);
    // 6. out = 2 * e@centT - e_sq - c_sq  (M=8192, N=16384, K=768)
    gemm_bt<1, 1><<<(BB / 128) * (CC / 128), 256, 0, stream>>>(eb, cb, out, esq, csq,
                                                               BB, CC, DD);
}